// Round 10
// baseline (1950.003 us; speedup 1.0000x reference)
//
#include <hip/hip_runtime.h>
#include <cstdint>
#include <cstddef>

// Problem constants
#define B_  128
#define T_  512
#define F_  128
#define U_  512
#define G3  1536   // 3*U
#define BU  (B_ * U_)

// Persistent partition: 8 groups (16 batch rows) x 32 WGs (16 units) = 256 WGs.
#define NGRP 8
#define MB   16
#define GN   32
#define UC   16

typedef __attribute__((ext_vector_type(8))) _Float16 half8;
typedef __attribute__((ext_vector_type(4))) float    f32x4;

union HU16 { _Float16 h; unsigned short us; };

__device__ __forceinline__ float sigmoidf_(float x) {
    return 1.0f / (1.0f + __expf(-x));
}

__device__ __forceinline__ void vm_drain() {
    asm volatile("s_waitcnt vmcnt(0)" ::: "memory");
}

__device__ __forceinline__ void lgkm_drain() {
    asm volatile("s_waitcnt lgkmcnt(0)" ::: "memory");
}

// ---- 16 x dwordx4 system-scope loads (LLC; bypass L1+L2 — proven R4/R6/R9) --
__device__ __forceinline__ void load_h16(const _Float16* aptr, half8* f) {
    asm volatile(
        "global_load_dwordx4 %0, %16, off offset:0 sc0 sc1\n\t"
        "global_load_dwordx4 %1, %16, off offset:64 sc0 sc1\n\t"
        "global_load_dwordx4 %2, %16, off offset:128 sc0 sc1\n\t"
        "global_load_dwordx4 %3, %16, off offset:192 sc0 sc1\n\t"
        "global_load_dwordx4 %4, %16, off offset:256 sc0 sc1\n\t"
        "global_load_dwordx4 %5, %16, off offset:320 sc0 sc1\n\t"
        "global_load_dwordx4 %6, %16, off offset:384 sc0 sc1\n\t"
        "global_load_dwordx4 %7, %16, off offset:448 sc0 sc1\n\t"
        "global_load_dwordx4 %8, %16, off offset:512 sc0 sc1\n\t"
        "global_load_dwordx4 %9, %16, off offset:576 sc0 sc1\n\t"
        "global_load_dwordx4 %10, %16, off offset:640 sc0 sc1\n\t"
        "global_load_dwordx4 %11, %16, off offset:704 sc0 sc1\n\t"
        "global_load_dwordx4 %12, %16, off offset:768 sc0 sc1\n\t"
        "global_load_dwordx4 %13, %16, off offset:832 sc0 sc1\n\t"
        "global_load_dwordx4 %14, %16, off offset:896 sc0 sc1\n\t"
        "global_load_dwordx4 %15, %16, off offset:960 sc0 sc1"
        : "=&v"(f[0]), "=&v"(f[1]), "=&v"(f[2]), "=&v"(f[3]),
          "=&v"(f[4]), "=&v"(f[5]), "=&v"(f[6]), "=&v"(f[7]),
          "=&v"(f[8]), "=&v"(f[9]), "=&v"(f[10]), "=&v"(f[11]),
          "=&v"(f[12]), "=&v"(f[13]), "=&v"(f[14]), "=&v"(f[15])
        : "v"((uint64_t)(uintptr_t)aptr)
        : "memory");
}

__device__ __forceinline__ void wait_h16(half8* f) {
    asm volatile(
        "s_waitcnt vmcnt(0)"
        : "+v"(f[0]), "+v"(f[1]), "+v"(f[2]), "+v"(f[3]),
          "+v"(f[4]), "+v"(f[5]), "+v"(f[6]), "+v"(f[7]),
          "+v"(f[8]), "+v"(f[9]), "+v"(f[10]), "+v"(f[11]),
          "+v"(f[12]), "+v"(f[13]), "+v"(f[14]), "+v"(f[15])
        :
        : "memory");
}

// ---- publish 4 consecutive-row f16 values (rows stride 1024 B), LLC scope ----
__device__ __forceinline__ void store_h4(_Float16* addr, unsigned v0, unsigned v1,
                                         unsigned v2, unsigned v3) {
    asm volatile(
        "global_store_short %0, %1, off sc0 sc1\n\t"
        "global_store_short %0, %2, off offset:1024 sc0 sc1\n\t"
        "global_store_short %0, %3, off offset:2048 sc0 sc1\n\t"
        "global_store_short %0, %4, off offset:3072 sc0 sc1"
        :: "v"((uint64_t)(uintptr_t)addr), "v"(v0), "v"(v1), "v"(v2), "v"(v3)
        : "memory");
}

// ---- flags: sc0 sc1 asm (only poll primitive proven fresh on this HW) ----
__device__ __forceinline__ void flag_set(unsigned* p, unsigned val) {
    asm volatile("global_store_dword %0, %1, off sc0 sc1"
                 :: "v"((uint64_t)(uintptr_t)p), "v"(val) : "memory");
}

__device__ __forceinline__ unsigned flag_get(const unsigned* p) {
    unsigned v;
    asm volatile("global_load_dword %0, %1, off sc0 sc1\n\ts_waitcnt vmcnt(0)"
                 : "=v"(v) : "v"((uint64_t)(uintptr_t)p) : "memory");
    return v;
}

__device__ __forceinline__ void poll_flags(const unsigned* base, int lane, unsigned tgt) {
    const unsigned* p = base + (lane & 31);
    while (!__all((int)(flag_get(p) >= tgt))) {}
}

// ---- LDS progress counters (workgroup scope) ----
__device__ __forceinline__ int lds_ld(const int* p) {
    return __hip_atomic_load(p, __ATOMIC_RELAXED, __HIP_MEMORY_SCOPE_WORKGROUP);
}
__device__ __forceinline__ void lds_st(int* p, int v) {
    __hip_atomic_store(p, v, __ATOMIC_RELAXED, __HIP_MEMORY_SCOPE_WORKGROUP);
}

// ---------------- cast x to f16 + zero pub/flag state ------------------------
__global__ void cast_init_kernel(const float* __restrict__ x,
                                 _Float16* __restrict__ xh,
                                 _Float16* __restrict__ h1pub,
                                 _Float16* __restrict__ h2pub,
                                 unsigned int* __restrict__ gbar) {
    size_t i      = (size_t)blockIdx.x * blockDim.x + threadIdx.x;
    size_t stride = (size_t)gridDim.x * blockDim.x;
    for (size_t idx = i; idx < (size_t)B_ * T_ * F_; idx += stride)
        xh[idx] = (_Float16)x[idx];
    for (size_t idx = i; idx < (size_t)3 * BU; idx += stride)
        h1pub[idx] = (_Float16)0.f;
    for (size_t idx = i; idx < (size_t)2 * BU; idx += stride)
        h2pub[idx] = (_Float16)0.f;
    if (blockIdx.x == 0)
        for (int idx = threadIdx.x; idx < 2048; idx += blockDim.x)
            gbar[idx] = 0u;
}

// ---------------- transpose+cast weights: (K,1536) f32 -> (1536,K) f16 -------
__global__ void transpose_cast_kernel(const float* __restrict__ in,
                                      _Float16* __restrict__ out, int K) {
    __shared__ float tile[32][33];
    int n0 = blockIdx.x * 32;
    int k0 = blockIdx.y * 32;
    int tx = threadIdx.x, ty = threadIdx.y;   // block (32, 8)
#pragma unroll
    for (int i = 0; i < 4; ++i)
        tile[ty + i * 8][tx] = in[(size_t)(k0 + ty + i * 8) * G3 + (n0 + tx)];
    __syncthreads();
#pragma unroll
    for (int i = 0; i < 4; ++i)
        out[(size_t)(n0 + ty + i * 8) * K + (k0 + tx)] =
            (_Float16)tile[tx][ty + i * 8];
}

// ---------------- GX1 = x @ W1 ----------------------------------------------
__global__ __launch_bounds__(256) void gemm_gx1_kernel(
    const _Float16* __restrict__ xh,
    const _Float16* __restrict__ w1t,
    _Float16* __restrict__ gx1) {
    int bx = blockIdx.x;          // 12288 = 1024 m-blocks * 12 n-blocks
    int mb = bx / 12, nb = bx % 12;
    int wave = threadIdx.x >> 6, lane = threadIdx.x & 63;
    int wm = wave >> 1, wn = wave & 1;
    int am = lane & 15, aq = lane >> 4;

    half8 af[2][4];
#pragma unroll
    for (int mt = 0; mt < 2; ++mt) {
        int mo = mb * 64 + wm * 32 + mt * 16 + am;
        int b = mo & 127, t = mo >> 7;
        const _Float16* ap = xh + ((size_t)b * T_ + t) * F_ + aq * 8;
#pragma unroll
        for (int kc = 0; kc < 4; ++kc)
            af[mt][kc] = *(const half8*)(ap + kc * 32);
    }

#pragma unroll
    for (int nt = 0; nt < 4; ++nt) {
        int n0 = nb * 128 + wn * 64 + nt * 16;
        f32x4 acc0 = {0.f, 0.f, 0.f, 0.f};
        f32x4 acc1 = {0.f, 0.f, 0.f, 0.f};
#pragma unroll
        for (int kc = 0; kc < 4; ++kc) {
            half8 bf = *(const half8*)(w1t + (size_t)(n0 + am) * F_ + kc * 32 + aq * 8);
            acc0 = __builtin_amdgcn_mfma_f32_16x16x32_f16(af[0][kc], bf, acc0, 0, 0, 0);
            acc1 = __builtin_amdgcn_mfma_f32_16x16x32_f16(af[1][kc], bf, acc1, 0, 0, 0);
        }
        int col = lane & 15, rb = (lane >> 4) * 4;
        int mbase0 = mb * 64 + wm * 32 + 0 * 16;
        int mbase1 = mb * 64 + wm * 32 + 1 * 16;
#pragma unroll
        for (int i = 0; i < 4; ++i) {
            gx1[(size_t)(mbase0 + rb + i) * G3 + n0 + col] = (_Float16)acc0[i];
            gx1[(size_t)(mbase1 + rb + i) * G3 + n0 + col] = (_Float16)acc1[i];
        }
    }
}

// ---------------- persistent 2-layer GRU: FREE-RUNNING wave pipelines --------
// wave0 (r=0..511): poll flag1>=r; load h1_{r-1}; rec1 mfma; in-lane combine;
//   publish h1_r (slot r%3) + flag1=r+1; then relay loaded panel to LDS A-ring
//   (slot r&1) + prog0=r+1.   [h1 serial chain — the critical path]
// wave1 (r=1..512): A-frags from LDS ring (gx2_{r-1} = h1_{r-1} @ W2slice),
//   scr[(r-1)&1] write, prog1=r. Last step (r=512) loads h1_511 from global.
// wave2 (s=0..511): wait prog1>=s+1; poll flag2>=s; load h2_{s-1}; rec2 mfma;
//   combine with scr[s&1]; publish h2_s (slot s&1) + flag2=s+1; prog2=s+1.
// NO __syncthreads in the loops — chains overlap instead of adding.
// WAR proofs: h1 3-deep (flag1>=r => all WGs' round-(r-1) loads drained);
// h2 2-deep (flag2>=s covers step-(s-1) loads); A-ring 2-deep (prog1>=r-2);
// scr 2-deep (prog2>=r-2). Deadlock-free by induction on global step order.
__global__ __launch_bounds__(192, 1) void gru_persist_kernel(
    const _Float16* __restrict__ gx1,
    const _Float16* __restrict__ u1t,
    const _Float16* __restrict__ w2t,
    const _Float16* __restrict__ u2t,
    const float* __restrict__ bi1, const float* __restrict__ br1,
    const float* __restrict__ bi2, const float* __restrict__ br2,
    _Float16* __restrict__ h1pub,      // 3 x (128,512) f16
    _Float16* __restrict__ h2pub,      // 2 x (128,512) f16
    float* __restrict__ h2fin,         // (128,512) f32
    unsigned int* __restrict__ gbar) {
    __shared__ _Float16 acp[2 * 16 * 512];   // 32 KB A-fragment relay ring
    __shared__ float    scr[2 * 3 * 272];    // 6.5 KB gx2 ring
    __shared__ int      prog[16];            // [0]=w0, [1]=w1, [2]=w2

    const int tid  = threadIdx.x;
    const int bx   = blockIdx.x;
    const int grp  = bx & 7;
    const int jj   = bx >> 3;
    const int wave = tid >> 6, lane = tid & 63;
    const int row0 = grp * MB;
    const int u0   = jj * UC;

    unsigned* flag1 = gbar + 512  + (size_t)grp * 32;
    unsigned* flag2 = gbar + 1024 + (size_t)grp * 32;
    unsigned* myflag1 = flag1 + jj;
    unsigned* myflag2 = flag2 + jj;

    const int col = lane & 15;
    const int rb4 = (lane >> 4) * 4;
    const int aq  = lane >> 4;
    const size_t a_elem = (size_t)(row0 + col) * U_ + aq * 8;
    const int u = u0 + col;

    // loop-invariant weight fragments (48 half8/wave)
    const _Float16* wsrc = (wave == 0) ? u1t : (wave == 1) ? w2t : u2t;
    half8 bfr[3][16];
#pragma unroll
    for (int g = 0; g < 3; ++g)
#pragma unroll
        for (int kc = 0; kc < 16; ++kc)
            bfr[g][kc] = *(const half8*)(
                wsrc + (size_t)(g * U_ + u0 + col) * U_ + kc * 32 + aq * 8);

    if (tid < 16) prog[tid] = 0;
    __syncthreads();

    if (wave == 0) {
        const float zb  = bi1[u] + br1[u];
        const float rb_ = bi1[U_ + u] + br1[U_ + u];
        const float hbi = bi1[2 * U_ + u];
        const float hbr = br1[2 * U_ + u];
        _Float16 pgz[4], pgr[4], pgh[4];
        {
            const _Float16* g0 = gx1 + ((size_t)0 * B_ + row0 + rb4) * G3;
#pragma unroll
            for (int i = 0; i < 4; ++i) {
                pgz[i] = g0[(size_t)i * G3 + u];
                pgr[i] = g0[(size_t)i * G3 + U_ + u];
                pgh[i] = g0[(size_t)i * G3 + 2 * U_ + u];
            }
        }
        float st[4] = {0.f, 0.f, 0.f, 0.f};

        for (int r = 0; r < T_; ++r) {
            // prefetch next gx1 BEFORE poll — HBM latency hides under discovery
            _Float16 ngz[4], ngr[4], ngh[4];
            bool pf = (r + 1 < T_);
            if (pf) {
                const _Float16* g = gx1 + ((size_t)(r + 1) * B_ + row0 + rb4) * G3;
#pragma unroll
                for (int i = 0; i < 4; ++i) {
                    ngz[i] = g[(size_t)i * G3 + u];
                    ngr[i] = g[(size_t)i * G3 + U_ + u];
                    ngh[i] = g[(size_t)i * G3 + 2 * U_ + u];
                }
            }
            poll_flags(flag1, lane, (unsigned)r);
            half8 f[16];
            load_h16(h1pub + (size_t)((r + 2) % 3) * BU + a_elem, f);  // h1_{r-1}
            wait_h16(f);
            f32x4 a0 = {0.f, 0.f, 0.f, 0.f};
            f32x4 a1 = {0.f, 0.f, 0.f, 0.f};
            f32x4 a2 = {0.f, 0.f, 0.f, 0.f};
#pragma unroll
            for (int kc = 0; kc < 16; ++kc) {
                a0 = __builtin_amdgcn_mfma_f32_16x16x32_f16(f[kc], bfr[0][kc], a0, 0, 0, 0);
                a1 = __builtin_amdgcn_mfma_f32_16x16x32_f16(f[kc], bfr[1][kc], a1, 0, 0, 0);
                a2 = __builtin_amdgcn_mfma_f32_16x16x32_f16(f[kc], bfr[2][kc], a2, 0, 0, 0);
            }
            unsigned pv[4];
#pragma unroll
            for (int i = 0; i < 4; ++i) {
                float z  = sigmoidf_((float)pgz[i] + a0[i] + zb);
                float rg = sigmoidf_((float)pgr[i] + a1[i] + rb_);
                float hh = fmaxf(0.f, (float)pgh[i] + hbi + rg * (a2[i] + hbr));
                st[i] = z * st[i] + (1.f - z) * hh;
                HU16 c; c.h = (_Float16)st[i]; pv[i] = c.us;
            }
            _Float16* dst = h1pub + (size_t)(r % 3) * BU +
                            (size_t)(row0 + rb4) * U_ + u;
            store_h4(dst, pv[0], pv[1], pv[2], pv[3]);
            vm_drain();
            if (lane == 0) flag_set(myflag1, (unsigned)(r + 1));
            if (pf) {
#pragma unroll
                for (int i = 0; i < 4; ++i) {
                    pgz[i] = ngz[i]; pgr[i] = ngr[i]; pgh[i] = ngh[i];
                }
            }
            // off-critical-path: relay h1_{r-1} panel to wave1 via LDS ring
            while (lds_ld(&prog[1]) < r - 2) {}
            _Float16* ab = acp + (size_t)(r & 1) * (16 * 512);
#pragma unroll
            for (int kc = 0; kc < 16; ++kc)
                *(half8*)(ab + kc * 512 + lane * 8) = f[kc];
            lgkm_drain();
            lds_st(&prog[0], r + 1);
        }
    } else if (wave == 1) {
        for (int r = 1; r < T_; ++r) {
            while (lds_ld(&prog[0]) < r + 1) {}
            while (lds_ld(&prog[2]) < r - 2) {}
            const _Float16* ab = acp + (size_t)(r & 1) * (16 * 512);
            half8 f[16];
#pragma unroll
            for (int kc = 0; kc < 16; ++kc)
                f[kc] = *(const half8*)(ab + kc * 512 + lane * 8);
            f32x4 a0 = {0.f, 0.f, 0.f, 0.f};
            f32x4 a1 = {0.f, 0.f, 0.f, 0.f};
            f32x4 a2 = {0.f, 0.f, 0.f, 0.f};
#pragma unroll
            for (int kc = 0; kc < 16; ++kc) {
                a0 = __builtin_amdgcn_mfma_f32_16x16x32_f16(f[kc], bfr[0][kc], a0, 0, 0, 0);
                a1 = __builtin_amdgcn_mfma_f32_16x16x32_f16(f[kc], bfr[1][kc], a1, 0, 0, 0);
                a2 = __builtin_amdgcn_mfma_f32_16x16x32_f16(f[kc], bfr[2][kc], a2, 0, 0, 0);
            }
            float* sp = scr + (size_t)((r - 1) & 1) * 3 * 272;
#pragma unroll
            for (int i = 0; i < 4; ++i) {
                sp[0 * 272 + (rb4 + i) * 17 + col] = a0[i];
                sp[1 * 272 + (rb4 + i) * 17 + col] = a1[i];
                sp[2 * 272 + (rb4 + i) * 17 + col] = a2[i];
            }
            lgkm_drain();
            lds_st(&prog[1], r);
        }
        {   // final step r=512: gx2_511 needs h1_511 (no relay) — global load
            const int r = T_;
            while (lds_ld(&prog[2]) < r - 2) {}
            poll_flags(flag1, lane, (unsigned)T_);
            half8 f[16];
            load_h16(h1pub + (size_t)((T_ - 1) % 3) * BU + a_elem, f);
            wait_h16(f);
            f32x4 a0 = {0.f, 0.f, 0.f, 0.f};
            f32x4 a1 = {0.f, 0.f, 0.f, 0.f};
            f32x4 a2 = {0.f, 0.f, 0.f, 0.f};
#pragma unroll
            for (int kc = 0; kc < 16; ++kc) {
                a0 = __builtin_amdgcn_mfma_f32_16x16x32_f16(f[kc], bfr[0][kc], a0, 0, 0, 0);
                a1 = __builtin_amdgcn_mfma_f32_16x16x32_f16(f[kc], bfr[1][kc], a1, 0, 0, 0);
                a2 = __builtin_amdgcn_mfma_f32_16x16x32_f16(f[kc], bfr[2][kc], a2, 0, 0, 0);
            }
            float* sp = scr + (size_t)((r - 1) & 1) * 3 * 272;
#pragma unroll
            for (int i = 0; i < 4; ++i) {
                sp[0 * 272 + (rb4 + i) * 17 + col] = a0[i];
                sp[1 * 272 + (rb4 + i) * 17 + col] = a1[i];
                sp[2 * 272 + (rb4 + i) * 17 + col] = a2[i];
            }
            lgkm_drain();
            lds_st(&prog[1], r);
        }
    } else {
        const float zb  = bi2[u] + br2[u];
        const float rb_ = bi2[U_ + u] + br2[U_ + u];
        const float hbi = bi2[2 * U_ + u];
        const float hbr = br2[2 * U_ + u];
        float st[4] = {0.f, 0.f, 0.f, 0.f};

        for (int s = 0; s < T_; ++s) {
            while (lds_ld(&prog[1]) < s + 1) {}
            poll_flags(flag2, lane, (unsigned)s);
            half8 f[16];
            load_h16(h2pub + (size_t)((s + 1) & 1) * BU + a_elem, f);  // h2_{s-1}
            wait_h16(f);
            f32x4 a0 = {0.f, 0.f, 0.f, 0.f};
            f32x4 a1 = {0.f, 0.f, 0.f, 0.f};
            f32x4 a2 = {0.f, 0.f, 0.f, 0.f};
#pragma unroll
            for (int kc = 0; kc < 16; ++kc) {
                a0 = __builtin_amdgcn_mfma_f32_16x16x32_f16(f[kc], bfr[0][kc], a0, 0, 0, 0);
                a1 = __builtin_amdgcn_mfma_f32_16x16x32_f16(f[kc], bfr[1][kc], a1, 0, 0, 0);
                a2 = __builtin_amdgcn_mfma_f32_16x16x32_f16(f[kc], bfr[2][kc], a2, 0, 0, 0);
            }
            const float* sp = scr + (size_t)(s & 1) * 3 * 272;   // gx2_s
            unsigned pv[4];
#pragma unroll
            for (int i = 0; i < 4; ++i) {
                int ro = (rb4 + i) * 17 + col;
                float z  = sigmoidf_(sp[0 * 272 + ro] + a0[i] + zb);
                float rg = sigmoidf_(sp[1 * 272 + ro] + a1[i] + rb_);
                float hh = fmaxf(0.f, sp[2 * 272 + ro] + hbi + rg * (a2[i] + hbr));
                st[i] = z * st[i] + (1.f - z) * hh;
                HU16 c; c.h = (_Float16)st[i]; pv[i] = c.us;
            }
            _Float16* dst = h2pub + (size_t)(s & 1) * BU +
                            (size_t)(row0 + rb4) * U_ + u;
            store_h4(dst, pv[0], pv[1], pv[2], pv[3]);
            vm_drain();
            if (lane == 0) flag_set(myflag2, (unsigned)(s + 1));
            lgkm_drain();                 // scr reads complete before release
            lds_st(&prog[2], s + 1);
            if (s == T_ - 1) {
#pragma unroll
                for (int i = 0; i < 4; ++i)
                    h2fin[(size_t)(row0 + rb4 + i) * U_ + u] = st[i];
            }
        }
    }
}

// ---------------- head: out = h2_final @ Wd + bd -----------------------------
__global__ void head_kernel(const float* __restrict__ h2fin,
                            const float* __restrict__ Wd,
                            const float* __restrict__ bd,
                            float* __restrict__ out) {
    int b = blockIdx.x;
    int lane = threadIdx.x;   // 64
    float s = 0.f;
#pragma unroll
    for (int u = lane; u < U_; u += 64)
        s += h2fin[(size_t)b * U_ + u] * Wd[u];
#pragma unroll
    for (int off = 32; off > 0; off >>= 1)
        s += __shfl_down(s, off, 64);
    if (lane == 0) out[b] = s + bd[0];
}

// ---------------- launch -----------------------------------------------------
extern "C" void kernel_launch(void* const* d_in, const int* in_sizes, int n_in,
                              void* d_out, int out_size, void* d_ws, size_t ws_size,
                              hipStream_t stream) {
    (void)in_sizes; (void)n_in; (void)out_size; (void)ws_size;

    const float* x   = (const float*)d_in[0];
    const float* W1  = (const float*)d_in[1];
    const float* U1  = (const float*)d_in[2];
    const float* bi1 = (const float*)d_in[3];
    const float* br1 = (const float*)d_in[4];
    const float* W2  = (const float*)d_in[5];
    const float* U2  = (const float*)d_in[6];
    const float* bi2 = (const float*)d_in[7];
    const float* br2 = (const float*)d_in[8];
    const float* Wd  = (const float*)d_in[9];
    const float* bd  = (const float*)d_in[10];

    char* w = (char*)d_ws;
    constexpr size_t OFF_XH   = 0;
    constexpr size_t OFF_W1T  = OFF_XH  + (size_t)B_ * T_ * F_ * 2;
    constexpr size_t OFF_U1T  = OFF_W1T + (size_t)G3 * F_ * 2;
    constexpr size_t OFF_W2T  = OFF_U1T + (size_t)G3 * U_ * 2;
    constexpr size_t OFF_U2T  = OFF_W2T + (size_t)G3 * U_ * 2;
    constexpr size_t OFF_GX1  = OFF_U2T + (size_t)G3 * U_ * 2;
    constexpr size_t OFF_H1P  = OFF_GX1 + (size_t)T_ * B_ * G3 * 2;
    constexpr size_t OFF_H2P  = OFF_H1P + (size_t)3 * BU * 2;
    constexpr size_t OFF_H2F  = OFF_H2P + (size_t)2 * BU * 2;
    constexpr size_t OFF_BAR  = OFF_H2F + (size_t)BU * 4;

    _Float16* xh   = (_Float16*)(w + OFF_XH);
    _Float16* w1t  = (_Float16*)(w + OFF_W1T);
    _Float16* u1t  = (_Float16*)(w + OFF_U1T);
    _Float16* w2t  = (_Float16*)(w + OFF_W2T);
    _Float16* u2t  = (_Float16*)(w + OFF_U2T);
    _Float16* gx1  = (_Float16*)(w + OFF_GX1);
    _Float16* h1p  = (_Float16*)(w + OFF_H1P);
    _Float16* h2p  = (_Float16*)(w + OFF_H2P);
    float*    h2f  = (float*)   (w + OFF_H2F);
    unsigned int* gbar = (unsigned int*)(w + OFF_BAR);

    cast_init_kernel<<<1024, 256, 0, stream>>>(x, xh, h1p, h2p, gbar);

    dim3 tb(32, 8);
    transpose_cast_kernel<<<dim3(48, 4),  tb, 0, stream>>>(W1, w1t, F_);
    transpose_cast_kernel<<<dim3(48, 16), tb, 0, stream>>>(U1, u1t, U_);
    transpose_cast_kernel<<<dim3(48, 16), tb, 0, stream>>>(W2, w2t, U_);
    transpose_cast_kernel<<<dim3(48, 16), tb, 0, stream>>>(U2, u2t, U_);

    gemm_gx1_kernel<<<12288, 256, 0, stream>>>(xh, w1t, gx1);

    gru_persist_kernel<<<256, 192, 0, stream>>>(gx1, u1t, w2t, u2t,
                                                bi1, br1, bi2, br2,
                                                h1p, h2p, h2f, gbar);

    head_kernel<<<128, 64, 0, stream>>>(h2f, Wd, bd, (float*)d_out);
}